// Round 9
// baseline (293.486 us; speedup 1.0000x reference)
//
#include <hip/hip_runtime.h>

typedef __bf16 bf16x8 __attribute__((ext_vector_type(8)));
typedef __bf16 bf16x4 __attribute__((ext_vector_type(4)));
typedef float  f32x4  __attribute__((ext_vector_type(4)));

#define MFMA16(a,b,c) __builtin_amdgcn_mfma_f32_16x16x32_bf16((a),(b),(c),0,0,0)

constexpr int B_ = 256, T_ = 200, DM = 2048, DK = 128;
constexpr int VT_STRIDE = 208;      // Vt[b][v][t], t padded 200->208

// ws layout (bytes)
constexpr size_t OFF_W = 0;                       // Wcat bf16 [384][2048] = 1,572,864
constexpr size_t OFF_Q = 1572864;                 // Q bf16 [51200][128] = 13,107,200
constexpr size_t OFF_K = OFF_Q + 13107200;        // K bf16 [51200][128]
constexpr size_t OFF_V = OFF_K + 13107200;        // Vt bf16 [256][128][208] = 13,631,488

#define GLOAD_LDS16(G, L)                                                     \
  __builtin_amdgcn_global_load_lds(                                           \
      (const __attribute__((address_space(1))) void*)(G),                     \
      (__attribute__((address_space(3))) void*)(L), 16, 0, 0)

// ---------------- weight conversion: Wq|Wk|Wv fp32 -> Wcat bf16 [384][2048] ----------------
__global__ __launch_bounds__(256) void wconv_kernel(const float* __restrict__ Wq,
                                                    const float* __restrict__ Wk,
                                                    const float* __restrict__ Wv,
                                                    __bf16* __restrict__ Wcat) {
  int idx = (blockIdx.x * 256 + threadIdx.x) * 4;   // < 384*2048 = 786432
  int sel = idx >> 18;                              // /262144 -> 0,1,2
  const float* base = (sel == 0) ? Wq : (sel == 1) ? Wk : Wv;
  float4 f = *(const float4*)(base + (idx - (sel << 18)));
  bf16x4 o;
  o[0] = (__bf16)f.x; o[1] = (__bf16)f.y; o[2] = (__bf16)f.z; o[3] = (__bf16)f.w;
  *(bf16x4*)(Wcat + idx) = o;
}

// ---------------- projection GEMM: C[51200][384] = q(fp32->bf16) @ Wcat^T ----------------
// BM=64, BN=384 (full N -> q HBM-read exactly once), BK=32, 512 threads (8 waves 2m x 4n,
// wave tile 32x96, acc=48 AGPR). LDS 56 KB dbuf + reg cap 128 -> TWO blocks/CU (m114
// cross-block overlap). A is reg-staged (global fp32 -> cvt -> ds_write bf16, T14 split:
// load issued ~1.5 iters early, cvt after COMPUTE); B via global_load_lds with COUNTED
// vmcnt(5) (issue order B-then-A so waiting B(t) leaves A(t+1) in flight). B is L2-resident
// (Wcat 1.5 MB) so its 1-iter lead suffices; A gets the long HBM lead. XOR swizzle on 16-B
// chunks, both sides (rule #21): phys_chunk = logical ^ ((row>>1)&3) for A-write/A-read/
// B-source/B-read -> all frag reads phase-conflict-free.
__global__ __launch_bounds__(512, 4) void proj_kernel(const float* __restrict__ q,
                                                      const __bf16* __restrict__ Wcat,
                                                      __bf16* __restrict__ Qo,
                                                      __bf16* __restrict__ Ko,
                                                      __bf16* __restrict__ Vt) {
  // bufA0 @0 (4KB), bufA1 @4096, bufB0 @8192 (24KB), bufB1 @32768; total 56 KB
  __shared__ alignas(16) char smem[57344];

  const int tid  = threadIdx.x;
  const int lane = tid & 63;
  const int w    = tid >> 6;
  const int wm   = w >> 2, wn = w & 3;
  const int lhi  = lane >> 4, llo = lane & 15;
  const int m0   = blockIdx.x * 64;

  f32x4 acc[2][6];
#pragma unroll
  for (int i = 0; i < 2; ++i)
#pragma unroll
    for (int j = 0; j < 6; ++j) acc[i][j] = {0.f, 0.f, 0.f, 0.f};

  // A reg-stage: thread -> row = tid>>3 (0..63), quad qd = tid&7 (4 fp32 = 16 B)
  const int arow = tid >> 3, aqd = tid & 7;
  const float* aptr = q + (size_t)(m0 + arow) * DM + aqd * 4;
  // A LDS write (swizzled, b64): byte = row*64 + phys16(qd>>1)^swz_row *16 + (qd&1)*8
  const int awoff = arow * 64 + (((aqd >> 1) ^ ((arow >> 1) & 3)) << 4) + (aqd & 1) * 8;
  // B staging: 3 rounds of 128 rows; row = (tid>>2)+128r, src chunk = (tid&3)^((tid>>3)&3)
  const __bf16* bgbase = Wcat + (size_t)(tid >> 2) * DM
                              + (((tid & 3) ^ ((tid >> 3) & 3)) << 3);
  // frag-read offsets: phys chunk = lhi ^ ((llo>>1)&3) (row terms vanish mod 4)
  const int swz   = (llo >> 1) & 3;
  const int aoff0 = (wm * 32 + llo) * 64 + ((lhi ^ swz) << 4);          // i stride 1024
  const int boff  = (wn * 96 + llo) * 64 + ((lhi ^ swz) << 4);          // j stride 1024

  f32x4 aset0, aset1;   // A double reg set (static names, rule #20)

#define B_ISSUE(BUF, K0)                                                      \
  {                                                                           \
    char* lb_ = smem + 8192 + (BUF) * 24576 + tid * 16;                       \
    _Pragma("unroll")                                                         \
    for (int r = 0; r < 3; ++r)                                               \
      GLOAD_LDS16(bgbase + (size_t)r * 128 * DM + (K0), lb_ + r * 8192);      \
  }

#define A_ISSUE(SET, K0) { (SET) = *(const f32x4*)(aptr + (K0)); }

#define A_PUB(SET, BUF)                                                       \
  {                                                                           \
    __builtin_amdgcn_sched_barrier(0);                                        \
    bf16x4 t4;                                                                \
    t4[0] = (__bf16)(SET)[0]; t4[1] = (__bf16)(SET)[1];                       \
    t4[2] = (__bf16)(SET)[2]; t4[3] = (__bf16)(SET)[3];                       \
    *(bf16x4*)(smem + (BUF) * 4096 + awoff) = t4;                             \
  }

#define COMPUTE(BUF)                                                          \
  {                                                                           \
    const char* la_ = smem + (BUF) * 4096;                                    \
    const char* lb_ = smem + 8192 + (BUF) * 24576;                            \
    bf16x8 af0 = *(const bf16x8*)(la_ + aoff0);                               \
    bf16x8 af1 = *(const bf16x8*)(la_ + aoff0 + 1024);                        \
    bf16x8 bfr[6];                                                            \
    _Pragma("unroll")                                                         \
    for (int j = 0; j < 6; ++j) bfr[j] = *(const bf16x8*)(lb_ + boff + j * 1024); \
    _Pragma("unroll")                                                         \
    for (int j = 0; j < 6; ++j) {                                             \
      acc[0][j] = MFMA16(af0, bfr[j], acc[0][j]);                             \
      acc[1][j] = MFMA16(af1, bfr[j], acc[1][j]);                             \
    }                                                                         \
  }

#define VMW(N) asm volatile("s_waitcnt vmcnt(" #N ")" ::: "memory")
#define LGKM0() asm volatile("s_waitcnt lgkmcnt(0)" ::: "memory")
#define BARRIER() __builtin_amdgcn_s_barrier()

  // ---- prologue: tile 0 into buf0; A(1) in flight ----
  B_ISSUE(0, 0);
  A_ISSUE(aset0, 0);
  A_ISSUE(aset1, 32);
  A_PUB(aset0, 0);            // compiler-waits A(0) (drains B(0) too: prologue only)
  LGKM0();
  BARRIER();

  // ---- bodies t=0..61 (pairs); steady invariant at entry of body t:
  //   tile t ready; A(t+1) regs in flight/landed; B(t) counted by vmcnt ----
  for (int tp = 0; tp < 31; ++tp) {
    const int t0 = tp * 2;
    { // body even t0 (BUF=0)
      B_ISSUE(1, (t0 + 1) * 32);
      A_ISSUE(aset0, (t0 + 2) * 32);
      VMW(5);                 // B(t0) landed; leaves A(t0+1),B(t0+1),A(t0+2)
      BARRIER();
      COMPUTE(0);
      A_PUB(aset1, 1);        // publish A(t0+1) (auto-wait leaves B/A newer)
      LGKM0();
      BARRIER();
    }
    { // body odd t0+1 (BUF=1)
      B_ISSUE(0, (t0 + 2) * 32);
      A_ISSUE(aset1, (t0 + 3) * 32);
      VMW(5);
      BARRIER();
      COMPUTE(1);
      A_PUB(aset0, 0);
      LGKM0();
      BARRIER();
    }
  }
  { // body 62 (BUF=0): no A(64)
    B_ISSUE(1, 63 * 32);
    VMW(4);                   // B(62) landed; leaves A(63),B(63)
    BARRIER();
    COMPUTE(0);
    A_PUB(aset1, 1);          // publish A(63)
    LGKM0();
    BARRIER();
  }
  { // body 63 (BUF=1): final
    VMW(0);
    BARRIER();
    COMPUTE(1);
  }
#undef B_ISSUE
#undef A_ISSUE
#undef A_PUB
#undef COMPUTE
#undef VMW
#undef LGKM0
#undef BARRIER

  // epilogue: col<128 -> Q, <256 -> K, else -> Vt transposed per batch
#pragma unroll
  for (int i = 0; i < 2; ++i) {
#pragma unroll
    for (int r = 0; r < 4; ++r) {
      int row = m0 + wm * 32 + i * 16 + lhi * 4 + r;   // bt index, always < 51200
      int b = row / 200;
      int t = row - b * 200;
#pragma unroll
      for (int j = 0; j < 6; ++j) {
        int col = wn * 96 + j * 16 + llo;
        __bf16 bv = (__bf16)acc[i][j][r];
        if (col < 128)       Qo[(size_t)row * DK + col] = bv;
        else if (col < 256)  Ko[(size_t)row * DK + (col - 128)] = bv;
        else                 Vt[((size_t)b * DK + (col - 256)) * VT_STRIDE + t] = bv;
      }
    }
  }
}

// ---------------- attention: one WG per (batch, 64-query block), templated on block ----------------
template <int QB>
__global__ __launch_bounds__(256, 1) void attn_kernel(const __bf16* __restrict__ Qg,
                                                      const __bf16* __restrict__ Kg,
                                                      const __bf16* __restrict__ Vt,
                                                      const int* __restrict__ padm,
                                                      float* __restrict__ out) {
  constexpr int Q0     = QB * 64;
  constexpr int KMAX   = (Q0 + 64 < T_) ? (Q0 + 64) : T_;   // 64,128,192,200 (causal bound)
  constexpr int KTILES = (KMAX + 15) / 16;                  // 4,8,12,13
  constexpr int KCC    = (KMAX + 31) / 32;                  // 2,4,6,7
  constexpr int KT16   = KTILES * 16;                       // 64,128,192,208
  constexpr int KP     = KCC * 32;                          // 64,128,192,224
  constexpr int VS     = KP + 8;                            // padded stride (bank spread)

  __shared__ __bf16 sK[KT16][136];
  __shared__ __bf16 sV[128][VS];       // V^T: [v][t]
  __shared__ __bf16 sP[4][16][VS];     // per-wave P transpose buffer
  __shared__ float  sMask[KT16];

  const int tid  = threadIdx.x;
  const int lane = tid & 63;
  const int w    = tid >> 6;
  const int b    = blockIdx.x;
  const int lhi  = lane >> 4, llo = lane & 15;

  // additive key mask: 0 valid, -1e30 for pad / t>=KMAX
  for (int t = tid; t < KT16; t += 256) {
    float mv = -1e30f;
    if (t < KMAX && padm[b * T_ + t] == 0) mv = 0.0f;
    sMask[t] = mv;
  }
  // stage K rows [0, KT16) (rows >= T_ clamped; they get masked anyway)
  for (int cid = tid; cid < KT16 * 16; cid += 256) {
    int t = cid >> 4, c = (cid & 15) * 8;
    int tg = (t < T_) ? t : (T_ - 1);
    *(bf16x8*)&sK[t][c] = *(const bf16x8*)(Kg + ((size_t)b * T_ + tg) * DK + c);
  }
  // stage V^T: [128][KP), zeros beyond Vt's 208 columns
  {
    constexpr int NCH = KP / 8;
    for (int cid = tid; cid < 128 * NCH; cid += 256) {
      int v = cid / NCH, t0 = (cid % NCH) * 8;
      bf16x8 val;
      if (t0 < VT_STRIDE) {
        val = *(const bf16x8*)(Vt + ((size_t)b * DK + v) * VT_STRIDE + t0);
      } else {
#pragma unroll
        for (int jz = 0; jz < 8; ++jz) val[jz] = (__bf16)0.0f;
      }
      *(bf16x8*)&sV[v][t0] = val;
    }
  }
  // zero P pad columns [KT16, KP) (only QB==3: 208..224)
  if constexpr (KT16 < KP) {
    constexpr int NC = (KP - KT16) / 8;
    for (int idx = tid; idx < 4 * 16 * NC; idx += 256) {
      int ww = idx / (16 * NC);
      int rem = idx % (16 * NC);
      int row = rem / NC, cc = (rem % NC) * 8;
      bf16x8 z;
#pragma unroll
      for (int jz = 0; jz < 8; ++jz) z[jz] = (__bf16)0.0f;
      *(bf16x8*)&sP[ww][row][KT16 + cc] = z;
    }
  }
  __syncthreads();

  // Q fragments in registers (A-frag: row = llo, k-chunk = lhi)
  const int q0w = Q0 + w * 16;
  bf16x8 qf[4];
  {
    int qrow = q0w + llo;
    if (qrow > T_ - 1) qrow = T_ - 1;
    const __bf16* qp = Qg + ((size_t)b * T_ + qrow) * DK + lhi * 8;
#pragma unroll
    for (int kk = 0; kk < 4; ++kk) qf[kk] = *(const bf16x8*)(qp + kk * 32);
  }

  // scores: S[16q x KT16] per wave, kept in registers
  float sc[KTILES][4];
  const float scale = 0.022097086912079608f;   // 1/sqrt(2048)
#pragma unroll
  for (int tt = 0; tt < KTILES; ++tt) {
    f32x4 s = {0.f, 0.f, 0.f, 0.f};
    const __bf16* kp = &sK[tt * 16 + llo][lhi * 8];
#pragma unroll
    for (int kk = 0; kk < 4; ++kk) {
      bf16x8 kf = *(const bf16x8*)(kp + kk * 32);
      s = MFMA16(qf[kk], kf, s);
    }
    const int t = tt * 16 + llo;
    const float madd = sMask[t];
#pragma unroll
    for (int r = 0; r < 4; ++r) {
      int qq = q0w + lhi * 4 + r;               // C layout: row = lhi*4+r, col = llo
      float v = fmaf(s[r], scale, madd);
      sc[tt][r] = (t > qq) ? -1e30f : v;        // overwrite-style causal mask (NaN-safe)
    }
  }

  // row softmax: reduce across the 16-lane col group per accumulator row
#pragma unroll
  for (int r = 0; r < 4; ++r) {
    float mm = -3e38f;
#pragma unroll
    for (int tt = 0; tt < KTILES; ++tt) mm = fmaxf(mm, sc[tt][r]);
#pragma unroll
    for (int off = 1; off < 16; off <<= 1) mm = fmaxf(mm, __shfl_xor(mm, off));
    float ss = 0.f;
#pragma unroll
    for (int tt = 0; tt < KTILES; ++tt) { float e = __expf(sc[tt][r] - mm); sc[tt][r] = e; ss += e; }
#pragma unroll
    for (int off = 1; off < 16; off <<= 1) ss += __shfl_xor(ss, off);
    float inv = 1.0f / ss;
#pragma unroll
    for (int tt = 0; tt < KTILES; ++tt) sc[tt][r] *= inv;
  }

  // P -> LDS (transpose through memory for the PV A-fragment)
#pragma unroll
  for (int tt = 0; tt < KTILES; ++tt) {
    int t = tt * 16 + llo;
#pragma unroll
    for (int r = 0; r < 4; ++r) sP[w][lhi * 4 + r][t] = (__bf16)sc[tt][r];
  }
  __syncthreads();

  // PV: out[16q x 128v] = P[16 x KP] @ V[KP x 128]
  f32x4 oacc[8];
#pragma unroll
  for (int vt = 0; vt < 8; ++vt) oacc[vt] = {0.f, 0.f, 0.f, 0.f};
#pragma unroll
  for (int kc = 0; kc < KCC; ++kc) {
    bf16x8 pa = *(const bf16x8*)&sP[w][llo][kc * 32 + lhi * 8];
#pragma unroll
    for (int vt = 0; vt < 8; ++vt) {
      bf16x8 vb = *(const bf16x8*)&sV[vt * 16 + llo][kc * 32 + lhi * 8];
      oacc[vt] = MFMA16(pa, vb, oacc[vt]);
    }
  }

  // write fp32 output
#pragma unroll
  for (int vt = 0; vt < 8; ++vt) {
#pragma unroll
    for (int r = 0; r < 4; ++r) {
      int qq = q0w + lhi * 4 + r;
      if (qq < T_) out[((size_t)b * T_ + qq) * DK + vt * 16 + llo] = oacc[vt][r];
    }
  }
}

extern "C" void kernel_launch(void* const* d_in, const int* in_sizes, int n_in,
                              void* d_out, int out_size, void* d_ws, size_t ws_size,
                              hipStream_t stream) {
  const float* q    = (const float*)d_in[0];
  const int*   padm = (const int*)d_in[1];
  const float* Wq   = (const float*)d_in[2];
  const float* Wk   = (const float*)d_in[3];
  const float* Wv   = (const float*)d_in[4];
  float* out        = (float*)d_out;

  char* ws = (char*)d_ws;
  __bf16* Wcat = (__bf16*)(ws + OFF_W);
  __bf16* Qb   = (__bf16*)(ws + OFF_Q);
  __bf16* Kb   = (__bf16*)(ws + OFF_K);
  __bf16* Vtb  = (__bf16*)(ws + OFF_V);

  wconv_kernel<<<768, 256, 0, stream>>>(Wq, Wk, Wv, Wcat);
  proj_kernel<<<800, 512, 0, stream>>>(q, Wcat, Qb, Kb, Vtb);
  attn_kernel<0><<<256, 256, 0, stream>>>(Qb, Kb, Vtb, padm, out);
  attn_kernel<1><<<256, 256, 0, stream>>>(Qb, Kb, Vtb, padm, out);
  attn_kernel<2><<<256, 256, 0, stream>>>(Qb, Kb, Vtb, padm, out);
  attn_kernel<3><<<256, 256, 0, stream>>>(Qb, Kb, Vtb, padm, out);
}

// Round 10
// 244.818 us; speedup vs baseline: 1.1988x; 1.1988x over previous
//
#include <hip/hip_runtime.h>

typedef __bf16 bf16x8 __attribute__((ext_vector_type(8)));
typedef __bf16 bf16x4 __attribute__((ext_vector_type(4)));
typedef float  f32x4  __attribute__((ext_vector_type(4)));

#define MFMA16(a,b,c) __builtin_amdgcn_mfma_f32_16x16x32_bf16((a),(b),(c),0,0,0)

constexpr int B_ = 256, T_ = 200, DM = 2048, DK = 128;
constexpr int VT_STRIDE = 208;      // Vt[b][v][t], t padded 200->208

// ws layout (bytes)
constexpr size_t OFF_W = 0;                       // Wcat bf16 [384][2048] = 1,572,864
constexpr size_t OFF_Q = 1572864;                 // Q bf16 [51200][128] = 13,107,200
constexpr size_t OFF_K = OFF_Q + 13107200;        // K bf16 [51200][128]
constexpr size_t OFF_V = OFF_K + 13107200;        // Vt bf16 [256][128][208] = 13,631,488

#define GLOAD_LDS16(G, L)                                                     \
  __builtin_amdgcn_global_load_lds(                                           \
      (const __attribute__((address_space(1))) void*)(G),                     \
      (__attribute__((address_space(3))) void*)(L), 16, 0, 0)

// ---------------- weight conversion: Wq|Wk|Wv fp32 -> Wcat bf16 [384][2048] ----------------
__global__ __launch_bounds__(256) void wconv_kernel(const float* __restrict__ Wq,
                                                    const float* __restrict__ Wk,
                                                    const float* __restrict__ Wv,
                                                    __bf16* __restrict__ Wcat) {
  int idx = (blockIdx.x * 256 + threadIdx.x) * 4;   // < 384*2048 = 786432
  int sel = idx >> 18;                              // /262144 -> 0,1,2
  const float* base = (sel == 0) ? Wq : (sel == 1) ? Wk : Wv;
  float4 f = *(const float4*)(base + (idx - (sel << 18)));
  bf16x4 o;
  o[0] = (__bf16)f.x; o[1] = (__bf16)f.y; o[2] = (__bf16)f.z; o[3] = (__bf16)f.w;
  *(bf16x4*)(Wcat + idx) = o;
}

// ---------------- projection GEMM: C[51200][384] = q(fp32->bf16) @ Wcat^T ----------------
// m97 geometry: 128x128 output tile, BK=64, 256 threads (4 waves 2m x 2n, wave tile 64x64,
// acc=64 AGPR, 32 MFMA/wave/K-step). Grid 1200 = 400 M-panels x 3 N-blocks (nb: 0=Q,1=K,2=V).
// XCD-aware job map: the 3 blocks of an M-panel are consecutive jobs on the SAME XCD ->
// shared A K-slices served from that XCD's L2 (HBM reads q ~once). Single-buffered 48 KB
// LDS -> 3 blocks/CU; cross-block overlap hides the __syncthreads stage drain (m97/m114).
// Both-sides XOR swizzle: A 16B-chunk cs^(row&15), B chunk cs^(row&7) -> frag reads 2-way.
__global__ __launch_bounds__(256) void proj_kernel(const float* __restrict__ q,
                                                   const __bf16* __restrict__ Wcat,
                                                   __bf16* __restrict__ Qo,
                                                   __bf16* __restrict__ Ko,
                                                   __bf16* __restrict__ Vt) {
  __shared__ alignas(16) char smem[49152];   // A fp32 [128][64] @0 (32 KB), B bf16 [128][64] @32768 (16 KB)

  const int tid  = threadIdx.x;
  const int lane = tid & 63;
  const int w    = tid >> 6;
  const int wm   = w >> 1, wn = w & 1;
  const int lhi  = lane >> 4, llo = lane & 15;

  // XCD-grouped job mapping (1200 = 8 XCDs x 150 jobs; 150 % 3 == 0 so triplets never straddle)
  const int d  = blockIdx.x;
  const int jj = (d & 7) * 150 + (d >> 3);
  const int mp = jj / 3, nb = jj - mp * 3;
  const int m0 = mp * 128;
  const int col0 = nb * 128;

  f32x4 acc[4][4];
#pragma unroll
  for (int i = 0; i < 4; ++i)
#pragma unroll
    for (int j = 0; j < 4; ++j) acc[i][j] = {0.f, 0.f, 0.f, 0.f};

  // A staging: 8 rounds of 16 rows; thread t -> row=(t>>4)+16r, slot-chunk cs=t&15,
  // global chunk g = cs ^ (row&15) = (t&15)^(t>>4)   (round-invariant)
  const float* agbase = q + (size_t)(m0 + (tid >> 4)) * DM
                          + (((tid & 15) ^ (tid >> 4)) << 2);
  // B staging: 4 rounds of 32 rows; row=(t>>3)+32r, cs=t&7, g = cs^(row&7) = (t&7)^((t>>3)&7)
  const __bf16* bgbase = Wcat + (size_t)(col0 + (tid >> 3)) * DM
                              + (((tid & 7) ^ ((tid >> 3) & 7)) << 3);

  constexpr int NK = DM / 64;   // 32 K-steps
  for (int t = 0; t < NK; ++t) {
    const int k0 = t * 64;
    // stage A (8 x gload_lds16) + B (4 x gload_lds16)
#pragma unroll
    for (int r = 0; r < 8; ++r)
      GLOAD_LDS16(agbase + (size_t)r * 16 * DM + k0, smem + tid * 16 + r * 4096);
#pragma unroll
    for (int r = 0; r < 4; ++r)
      GLOAD_LDS16(bgbase + (size_t)r * 32 * DM + k0, smem + 32768 + tid * 16 + r * 4096);
    __syncthreads();           // drain: tile t visible

#pragma unroll
    for (int kk = 0; kk < 2; ++kk) {
      bf16x8 af[4];
#pragma unroll
      for (int i = 0; i < 4; ++i) {
        const int row = wm * 64 + i * 16 + llo;
        const int c0 = kk * 8 + lhi * 2;
        f32x4 u = *(const f32x4*)(smem + row * 256 + (((c0 ^ llo) & 15) << 4));
        f32x4 v = *(const f32x4*)(smem + row * 256 + ((((c0 + 1) ^ llo) & 15) << 4));
        af[i][0]=(__bf16)u[0]; af[i][1]=(__bf16)u[1]; af[i][2]=(__bf16)u[2]; af[i][3]=(__bf16)u[3];
        af[i][4]=(__bf16)v[0]; af[i][5]=(__bf16)v[1]; af[i][6]=(__bf16)v[2]; af[i][7]=(__bf16)v[3];
      }
      bf16x8 bfr[4];
#pragma unroll
      for (int j = 0; j < 4; ++j) {
        const int row = wn * 64 + j * 16 + llo;
        const int c = kk * 4 + lhi;
        bfr[j] = *(const bf16x8*)(smem + 32768 + row * 128 + (((c ^ (llo & 7)) & 7) << 4));
      }
#pragma unroll
      for (int i = 0; i < 4; ++i)
#pragma unroll
        for (int j = 0; j < 4; ++j) acc[i][j] = MFMA16(af[i], bfr[j], acc[i][j]);
    }
    if (t + 1 < NK) __syncthreads();   // protect single buffer before next stage
  }

  // epilogue: nb selects destination (block-uniform branch)
  if (nb == 0) {
#pragma unroll
    for (int i = 0; i < 4; ++i)
#pragma unroll
      for (int r = 0; r < 4; ++r) {
        int row = m0 + wm * 64 + i * 16 + lhi * 4 + r;
#pragma unroll
        for (int j = 0; j < 4; ++j)
          Qo[(size_t)row * DK + wn * 64 + j * 16 + llo] = (__bf16)acc[i][j][r];
      }
  } else if (nb == 1) {
#pragma unroll
    for (int i = 0; i < 4; ++i)
#pragma unroll
      for (int r = 0; r < 4; ++r) {
        int row = m0 + wm * 64 + i * 16 + lhi * 4 + r;
#pragma unroll
        for (int j = 0; j < 4; ++j)
          Ko[(size_t)row * DK + wn * 64 + j * 16 + llo] = (__bf16)acc[i][j][r];
      }
  } else {
#pragma unroll
    for (int i = 0; i < 4; ++i)
#pragma unroll
      for (int r = 0; r < 4; ++r) {
        int row = m0 + wm * 64 + i * 16 + lhi * 4 + r;
        int b = row / 200;
        int t = row - b * 200;
#pragma unroll
        for (int j = 0; j < 4; ++j) {
          int col = wn * 64 + j * 16 + llo;
          Vt[((size_t)b * DK + col) * VT_STRIDE + t] = (__bf16)acc[i][j][r];
        }
      }
  }
}

// ---------------- attention: one WG per (batch, 64-query block), templated on block ----------------
template <int QB>
__global__ __launch_bounds__(256, 1) void attn_kernel(const __bf16* __restrict__ Qg,
                                                      const __bf16* __restrict__ Kg,
                                                      const __bf16* __restrict__ Vt,
                                                      const int* __restrict__ padm,
                                                      float* __restrict__ out) {
  constexpr int Q0     = QB * 64;
  constexpr int KMAX   = (Q0 + 64 < T_) ? (Q0 + 64) : T_;   // 64,128,192,200 (causal bound)
  constexpr int KTILES = (KMAX + 15) / 16;                  // 4,8,12,13
  constexpr int KCC    = (KMAX + 31) / 32;                  // 2,4,6,7
  constexpr int KT16   = KTILES * 16;                       // 64,128,192,208
  constexpr int KP     = KCC * 32;                          // 64,128,192,224
  constexpr int VS     = KP + 8;                            // padded stride (bank spread)

  __shared__ __bf16 sK[KT16][136];
  __shared__ __bf16 sV[128][VS];       // V^T: [v][t]
  __shared__ __bf16 sP[4][16][VS];     // per-wave P transpose buffer
  __shared__ float  sMask[KT16];

  const int tid  = threadIdx.x;
  const int lane = tid & 63;
  const int w    = tid >> 6;
  const int b    = blockIdx.x;
  const int lhi  = lane >> 4, llo = lane & 15;

  // additive key mask: 0 valid, -1e30 for pad / t>=KMAX
  for (int t = tid; t < KT16; t += 256) {
    float mv = -1e30f;
    if (t < KMAX && padm[b * T_ + t] == 0) mv = 0.0f;
    sMask[t] = mv;
  }
  // stage K rows [0, KT16) (rows >= T_ clamped; they get masked anyway)
  for (int cid = tid; cid < KT16 * 16; cid += 256) {
    int t = cid >> 4, c = (cid & 15) * 8;
    int tg = (t < T_) ? t : (T_ - 1);
    *(bf16x8*)&sK[t][c] = *(const bf16x8*)(Kg + ((size_t)b * T_ + tg) * DK + c);
  }
  // stage V^T: [128][KP), zeros beyond Vt's 208 columns
  {
    constexpr int NCH = KP / 8;
    for (int cid = tid; cid < 128 * NCH; cid += 256) {
      int v = cid / NCH, t0 = (cid % NCH) * 8;
      bf16x8 val;
      if (t0 < VT_STRIDE) {
        val = *(const bf16x8*)(Vt + ((size_t)b * DK + v) * VT_STRIDE + t0);
      } else {
#pragma unroll
        for (int jz = 0; jz < 8; ++jz) val[jz] = (__bf16)0.0f;
      }
      *(bf16x8*)&sV[v][t0] = val;
    }
  }
  // zero P pad columns [KT16, KP) (only QB==3: 208..224)
  if constexpr (KT16 < KP) {
    constexpr int NC = (KP - KT16) / 8;
    for (int idx = tid; idx < 4 * 16 * NC; idx += 256) {
      int ww = idx / (16 * NC);
      int rem = idx % (16 * NC);
      int row = rem / NC, cc = (rem % NC) * 8;
      bf16x8 z;
#pragma unroll
      for (int jz = 0; jz < 8; ++jz) z[jz] = (__bf16)0.0f;
      *(bf16x8*)&sP[ww][row][KT16 + cc] = z;
    }
  }
  __syncthreads();

  // Q fragments in registers (A-frag: row = llo, k-chunk = lhi)
  const int q0w = Q0 + w * 16;
  bf16x8 qf[4];
  {
    int qrow = q0w + llo;
    if (qrow > T_ - 1) qrow = T_ - 1;
    const __bf16* qp = Qg + ((size_t)b * T_ + qrow) * DK + lhi * 8;
#pragma unroll
    for (int kk = 0; kk < 4; ++kk) qf[kk] = *(const bf16x8*)(qp + kk * 32);
  }

  // scores: S[16q x KT16] per wave, kept in registers
  float sc[KTILES][4];
  const float scale = 0.022097086912079608f;   // 1/sqrt(2048)
#pragma unroll
  for (int tt = 0; tt < KTILES; ++tt) {
    f32x4 s = {0.f, 0.f, 0.f, 0.f};
    const __bf16* kp = &sK[tt * 16 + llo][lhi * 8];
#pragma unroll
    for (int kk = 0; kk < 4; ++kk) {
      bf16x8 kf = *(const bf16x8*)(kp + kk * 32);
      s = MFMA16(qf[kk], kf, s);
    }
    const int t = tt * 16 + llo;
    const float madd = sMask[t];
#pragma unroll
    for (int r = 0; r < 4; ++r) {
      int qq = q0w + lhi * 4 + r;               // C layout: row = lhi*4+r, col = llo
      float v = fmaf(s[r], scale, madd);
      sc[tt][r] = (t > qq) ? -1e30f : v;        // overwrite-style causal mask (NaN-safe)
    }
  }

  // row softmax: reduce across the 16-lane col group per accumulator row
#pragma unroll
  for (int r = 0; r < 4; ++r) {
    float mm = -3e38f;
#pragma unroll
    for (int tt = 0; tt < KTILES; ++tt) mm = fmaxf(mm, sc[tt][r]);
#pragma unroll
    for (int off = 1; off < 16; off <<= 1) mm = fmaxf(mm, __shfl_xor(mm, off));
    float ss = 0.f;
#pragma unroll
    for (int tt = 0; tt < KTILES; ++tt) { float e = __expf(sc[tt][r] - mm); sc[tt][r] = e; ss += e; }
#pragma unroll
    for (int off = 1; off < 16; off <<= 1) ss += __shfl_xor(ss, off);
    float inv = 1.0f / ss;
#pragma unroll
    for (int tt = 0; tt < KTILES; ++tt) sc[tt][r] *= inv;
  }

  // P -> LDS (transpose through memory for the PV A-fragment)
#pragma unroll
  for (int tt = 0; tt < KTILES; ++tt) {
    int t = tt * 16 + llo;
#pragma unroll
    for (int r = 0; r < 4; ++r) sP[w][lhi * 4 + r][t] = (__bf16)sc[tt][r];
  }
  __syncthreads();

  // PV: out[16q x 128v] = P[16 x KP] @ V[KP x 128]
  f32x4 oacc[8];
#pragma unroll
  for (int vt = 0; vt < 8; ++vt) oacc[vt] = {0.f, 0.f, 0.f, 0.f};
#pragma unroll
  for (int kc = 0; kc < KCC; ++kc) {
    bf16x8 pa = *(const bf16x8*)&sP[w][llo][kc * 32 + lhi * 8];
#pragma unroll
    for (int vt = 0; vt < 8; ++vt) {
      bf16x8 vb = *(const bf16x8*)&sV[vt * 16 + llo][kc * 32 + lhi * 8];
      oacc[vt] = MFMA16(pa, vb, oacc[vt]);
    }
  }

  // write fp32 output
#pragma unroll
  for (int vt = 0; vt < 8; ++vt) {
#pragma unroll
    for (int r = 0; r < 4; ++r) {
      int qq = q0w + lhi * 4 + r;
      if (qq < T_) out[((size_t)b * T_ + qq) * DK + vt * 16 + llo] = oacc[vt][r];
    }
  }
}

extern "C" void kernel_launch(void* const* d_in, const int* in_sizes, int n_in,
                              void* d_out, int out_size, void* d_ws, size_t ws_size,
                              hipStream_t stream) {
  const float* q    = (const float*)d_in[0];
  const int*   padm = (const int*)d_in[1];
  const float* Wq   = (const float*)d_in[2];
  const float* Wk   = (const float*)d_in[3];
  const float* Wv   = (const float*)d_in[4];
  float* out        = (float*)d_out;

  char* ws = (char*)d_ws;
  __bf16* Wcat = (__bf16*)(ws + OFF_W);
  __bf16* Qb   = (__bf16*)(ws + OFF_Q);
  __bf16* Kb   = (__bf16*)(ws + OFF_K);
  __bf16* Vtb  = (__bf16*)(ws + OFF_V);

  wconv_kernel<<<768, 256, 0, stream>>>(Wq, Wk, Wv, Wcat);
  proj_kernel<<<1200, 256, 0, stream>>>(q, Wcat, Qb, Kb, Vtb);
  attn_kernel<0><<<256, 256, 0, stream>>>(Qb, Kb, Vtb, padm, out);
  attn_kernel<1><<<256, 256, 0, stream>>>(Qb, Kb, Vtb, padm, out);
  attn_kernel<2><<<256, 256, 0, stream>>>(Qb, Kb, Vtb, padm, out);
  attn_kernel<3><<<256, 256, 0, stream>>>(Qb, Kb, Vtb, padm, out);
}